// Round 15
// baseline (66.778 us; speedup 1.0000x reference)
//
#include <hip/hip_runtime.h>

#define HH 4096
#define WW 4096
#define MAXK (1 << 20)      // == NRS * 64
#define NSP 4               // 1024-px spans per row
#define SPW 1024            // span width
#define NRS (HH * NSP)      // 16384 row-spans (1 per wave)
#define NBLK (NRS / 4)      // 4096 blocks, 4 waves each
#define GSPAN 256           // spans per group
#define NGRP (NRS / GSPAN)  // 64 groups

typedef int   v4i __attribute__((ext_vector_type(4)));
typedef float v4f __attribute__((ext_vector_type(4)));

// ---------------------------------------------------------------------------
// Kernel 1: 3x3 NMS. One WAVE per 1024-px row-span as FOUR lane-contiguous
// 256-px panels. Shuffle halos (panel boundaries via lane63<->lane0
// broadcasts), 3 broadcast scalar loads for span-edge columns. No LDS, no
// barriers, no atomics. Plain loads (NT load kills replay L3 residency),
// NT stores on mx (write-once). Clamp-to-edge == -inf SAME padding.
// XCD swizzle: 512 consecutive blocks (512 rows) per XCD.
// ---------------------------------------------------------------------------
__global__ __launch_bounds__(256, 8) void k_maxima(
    const float* __restrict__ rel, const float* __restrict__ rep,
    int* __restrict__ mx, unsigned short* __restrict__ masks,
    int* __restrict__ counts)
{
    const int tid  = threadIdx.x;
    const int lane = tid & 63;
    const int swz  = (blockIdx.x & 7) * (NBLK / 8) + (blockIdx.x >> 3);
    const int rs   = swz * 4 + (tid >> 6);     // row-span id, 0..NRS-1
    const int y    = rs >> 2;
    const int span = rs & (NSP - 1);
    const int cb   = span * SPW + lane * 4;    // panel-0 column

    const int xl = span ? span * SPW - 1 : 0;                    // left halo col
    const int xr = (span < NSP - 1) ? (span + 1) * SPW : WW - 1; // right halo col
    const int hx = (lane == 63) ? xr : xl;     // 2 cache lines, broadcast

    const float* rowC = rep + (size_t)y * WW;
    const float* rowU = rep + (size_t)(y > 0      ? y - 1 : 0     ) * WW;
    const float* rowD = rep + (size_t)(y < HH - 1 ? y + 1 : HH - 1) * WW;
    const float* rowV = rel + (size_t)y * WW;

    const float hu = rowU[hx], hc = rowC[hx], hd = rowD[hx];
    const float hvm = fmaxf(fmaxf(hu, hc), hd);

    v4f Cp[4], Vp[4], vm[4];
#pragma unroll
    for (int p = 0; p < 4; ++p) {
        const int c = cb + p * 256;
        const v4f U = *(const v4f*)(rowU + c);
        const v4f Cv = *(const v4f*)(rowC + c);
        const v4f D = *(const v4f*)(rowD + c);
        Vp[p] = *(const v4f*)(rowV + c);
        Cp[p] = Cv;
        vm[p].x = fmaxf(fmaxf(U.x, Cv.x), D.x);
        vm[p].y = fmaxf(fmaxf(U.y, Cv.y), D.y);
        vm[p].z = fmaxf(fmaxf(U.z, Cv.z), D.z);
        vm[p].w = fmaxf(fmaxf(U.w, Cv.w), D.w);
    }

    // horizontal halos: intra-panel shuffles + cross-panel broadcasts
    float lft[4], rgt[4];
#pragma unroll
    for (int p = 0; p < 4; ++p) {
        lft[p] = __shfl_up(vm[p].w, 1, 64);
        rgt[p] = __shfl_down(vm[p].x, 1, 64);
    }
    const float c01 = __shfl(vm[0].w, 63, 64);  // panel0 last -> panel1 left
    const float c12 = __shfl(vm[1].w, 63, 64);
    const float c23 = __shfl(vm[2].w, 63, 64);
    const float r01 = __shfl(vm[1].x, 0, 64);   // panel1 first -> panel0 right
    const float r12 = __shfl(vm[2].x, 0, 64);
    const float r23 = __shfl(vm[3].x, 0, 64);
    if (lane == 0)  { lft[0] = hvm; lft[1] = c01; lft[2] = c12; lft[3] = c23; }
    if (lane == 63) { rgt[3] = hvm; rgt[0] = r01; rgt[1] = r12; rgt[2] = r23; }

    unsigned int mask16 = 0;
#pragma unroll
    for (int p = 0; p < 4; ++p) {
        const v4f Cv = Cp[p], V = Vp[p], v = vm[p];
        unsigned int m = 0;
        if (Cv.x == fmaxf(fmaxf(lft[p], v.x), v.y) && Cv.x >= 0.7f && V.x >= 0.7f) m |= 1u;
        if (Cv.y == fmaxf(fmaxf(v.x, v.y), v.z)    && Cv.y >= 0.7f && V.y >= 0.7f) m |= 2u;
        if (Cv.z == fmaxf(fmaxf(v.y, v.z), v.w)    && Cv.z >= 0.7f && V.z >= 0.7f) m |= 4u;
        if (Cv.w == fmaxf(fmaxf(v.z, v.w), rgt[p]) && Cv.w >= 0.7f && V.w >= 0.7f) m |= 8u;

        v4i o;
        o.x = m & 1u; o.y = (m >> 1) & 1u; o.z = (m >> 2) & 1u; o.w = (m >> 3) & 1u;
        __builtin_nontemporal_store(o,
            reinterpret_cast<v4i*>(mx + (size_t)y * WW + cb + p * 256));

        mask16 |= m << (4 * p);
    }

    if (masks) masks[(size_t)rs * 64 + lane] = (unsigned short)mask16;

    int cnt = __popc(mask16);
#pragma unroll
    for (int off = 32; off; off >>= 1) cnt += __shfl_down(cnt, off, 64);
    if (lane == 0) counts[rs] = cnt;
}

// ---------------------------------------------------------------------------
// Kernel 2: per-group sums, NO atomics. 64 blocks x 64 threads; block g sums
// counts[g*256 .. g*256+256) -> gsum[g] (one writer).
// ---------------------------------------------------------------------------
__global__ __launch_bounds__(64) void k_gsum(const int* __restrict__ counts,
                                             int* __restrict__ gsum)
{
    const int g    = blockIdx.x;
    const int lane = threadIdx.x;
    const int4 a = *reinterpret_cast<const int4*>(counts + g * GSPAN + lane * 4);
    int s = a.x + a.y + a.z + a.w;
#pragma unroll
    for (int off = 32; off; off >>= 1) s += __shfl_xor(s, off, 64);
    if (lane == 0) gsum[g] = s;
}

// ---------------------------------------------------------------------------
// Offset recomputation (per wave, for span rs):
//   base  = scan(gsum)[group] + sum(counts[group_base .. rs))
//   total = sum(gsum)
// All reads L2-hot (256 B gsum + 1 KB counts slice).
// ---------------------------------------------------------------------------
__device__ __forceinline__ void span_offset(
    const int* __restrict__ counts, const int* __restrict__ gsum,
    int rs, int lane, int& base, int& total)
{
    const int gv = gsum[lane];          // 64 lanes <-> 64 groups
    int ginc = gv;
#pragma unroll
    for (int off = 1; off < 64; off <<= 1) {
        int n = __shfl_up(ginc, off, 64);
        if (lane >= off) ginc += n;
    }
    total = __shfl(ginc, 63, 64);
    const int g     = rs >> 8;
    const int gbase = __shfl(ginc - gv, g, 64);

    const int rl    = rs & (GSPAN - 1);
    const int cbase = rs & ~(GSPAN - 1);
    const int4 c  = *reinterpret_cast<const int4*>(counts + cbase + lane * 4);
    const int idx = lane * 4;
    int s = 0;
    s += (idx + 0 < rl) ? c.x : 0;
    s += (idx + 1 < rl) ? c.y : 0;
    s += (idx + 2 < rl) ? c.z : 0;
    s += (idx + 3 < rl) ? c.w : 0;
#pragma unroll
    for (int off = 32; off; off >>= 1) s += __shfl_xor(s, off, 64);
    base = gbase + s;
}

// ---------------------------------------------------------------------------
// Kernel 3a: ordered compaction, one WAVE per 1024-px span. Four-panel
// ordered prefix via two packed 16+16-bit scans. Fused -1 tail fill: span rs
// owns coord slots [rs*64, rs*64+64).
// ---------------------------------------------------------------------------
__global__ __launch_bounds__(256) void k_emit_ws(
    const unsigned short* __restrict__ masks, const int* __restrict__ counts,
    const int* __restrict__ gsum, int* __restrict__ oy, int* __restrict__ ox)
{
    const int tid  = threadIdx.x;
    const int lane = tid & 63;
    const int rs   = blockIdx.x * 4 + (tid >> 6);

    int base, total;
    span_offset(counts, gsum, rs, lane, base, total);

    const int slot = rs * 64 + lane;
    if (slot >= total) { oy[slot] = -1; ox[slot] = -1; }

    const unsigned int b = masks[(size_t)rs * 64 + lane];
    unsigned int m0 = b & 0xFu, m1 = (b >> 4) & 0xFu;
    unsigned int m2 = (b >> 8) & 0xFu, m3 = b >> 12;
    const int c0 = __popc(m0), c1 = __popc(m1), c2 = __popc(m2), c3 = __popc(m3);

    int incA = c0 | (c1 << 16);
    int incB = c2 | (c3 << 16);
#pragma unroll
    for (int off = 1; off < 64; off <<= 1) {
        int nA = __shfl_up(incA, off, 64);
        int nB = __shfl_up(incB, off, 64);
        if (lane >= off) { incA += nA; incB += nB; }
    }
    const int lastA = __shfl(incA, 63, 64);
    const int lastB = __shfl(incB, 63, 64);
    const int T0 = lastA & 0xFFFF;
    const int T1 = lastA >> 16;
    const int T2 = lastB & 0xFFFF;

    const int y  = rs >> 2;
    const int xb = (rs & (NSP - 1)) * SPW + lane * 4;

    int pos = base + (incA & 0xFFFF) - c0;                 // panel 0
    while (m0) {
        int bit = __ffs(m0) - 1; m0 &= m0 - 1;
        if (pos < MAXK) { oy[pos] = y; ox[pos] = xb + bit; }
        ++pos;
    }
    pos = base + T0 + (incA >> 16) - c1;                   // panel 1
    while (m1) {
        int bit = __ffs(m1) - 1; m1 &= m1 - 1;
        if (pos < MAXK) { oy[pos] = y; ox[pos] = xb + 256 + bit; }
        ++pos;
    }
    pos = base + T0 + T1 + (incB & 0xFFFF) - c2;           // panel 2
    while (m2) {
        int bit = __ffs(m2) - 1; m2 &= m2 - 1;
        if (pos < MAXK) { oy[pos] = y; ox[pos] = xb + 512 + bit; }
        ++pos;
    }
    pos = base + T0 + T1 + T2 + (incB >> 16) - c3;         // panel 3
    while (m3) {
        int bit = __ffs(m3) - 1; m3 &= m3 - 1;
        if (pos < MAXK) { oy[pos] = y; ox[pos] = xb + 768 + bit; }
        ++pos;
    }
}

// ---------------------------------------------------------------------------
// Kernel 3b: fallback — rebuild masks from the int32 maxima array.
// ---------------------------------------------------------------------------
__global__ __launch_bounds__(256) void k_emit_mx(
    const int* __restrict__ mx, const int* __restrict__ counts,
    const int* __restrict__ gsum, int* __restrict__ oy, int* __restrict__ ox)
{
    const int tid  = threadIdx.x;
    const int lane = tid & 63;
    const int rs   = blockIdx.x * 4 + (tid >> 6);
    const int y    = rs >> 2;
    const int xb   = (rs & (NSP - 1)) * SPW + lane * 4;

    int base, total;
    span_offset(counts, gsum, rs, lane, base, total);

    const int slot = rs * 64 + lane;
    if (slot >= total) { oy[slot] = -1; ox[slot] = -1; }

    unsigned int mm[4];
#pragma unroll
    for (int p = 0; p < 4; ++p) {
        const int4 f = *reinterpret_cast<const int4*>(
            mx + (size_t)y * WW + xb + p * 256);
        unsigned int m = 0;
        if (f.x) m |= 1u;  if (f.y) m |= 2u;
        if (f.z) m |= 4u;  if (f.w) m |= 8u;
        mm[p] = m;
    }
    unsigned int m0 = mm[0], m1 = mm[1], m2 = mm[2], m3 = mm[3];
    const int c0 = __popc(m0), c1 = __popc(m1), c2 = __popc(m2), c3 = __popc(m3);

    int incA = c0 | (c1 << 16);
    int incB = c2 | (c3 << 16);
#pragma unroll
    for (int off = 1; off < 64; off <<= 1) {
        int nA = __shfl_up(incA, off, 64);
        int nB = __shfl_up(incB, off, 64);
        if (lane >= off) { incA += nA; incB += nB; }
    }
    const int lastA = __shfl(incA, 63, 64);
    const int lastB = __shfl(incB, 63, 64);
    const int T0 = lastA & 0xFFFF;
    const int T1 = lastA >> 16;
    const int T2 = lastB & 0xFFFF;

    int pos = base + (incA & 0xFFFF) - c0;
    while (m0) {
        int bit = __ffs(m0) - 1; m0 &= m0 - 1;
        if (pos < MAXK) { oy[pos] = y; ox[pos] = xb + bit; }
        ++pos;
    }
    pos = base + T0 + (incA >> 16) - c1;
    while (m1) {
        int bit = __ffs(m1) - 1; m1 &= m1 - 1;
        if (pos < MAXK) { oy[pos] = y; ox[pos] = xb + 256 + bit; }
        ++pos;
    }
    pos = base + T0 + T1 + (incB & 0xFFFF) - c2;
    while (m2) {
        int bit = __ffs(m2) - 1; m2 &= m2 - 1;
        if (pos < MAXK) { oy[pos] = y; ox[pos] = xb + 512 + bit; }
        ++pos;
    }
    pos = base + T0 + T1 + T2 + (incB >> 16) - c3;
    while (m3) {
        int bit = __ffs(m3) - 1; m3 &= m3 - 1;
        if (pos < MAXK) { oy[pos] = y; ox[pos] = xb + 768 + bit; }
        ++pos;
    }
}

// ---------------------------------------------------------------------------
extern "C" void kernel_launch(void* const* d_in, const int* in_sizes, int n_in,
                              void* d_out, int out_size, void* d_ws, size_t ws_size,
                              hipStream_t stream)
{
    const float* rel = (const float*)d_in[0];   // reliability
    const float* rep = (const float*)d_in[1];   // repeatability

    int* out = (int*)d_out;
    int* mx  = out;                       // 4096*4096 maxima (int32 0/1)
    int* oy  = out + (size_t)HH * WW;     // 2^20 y coords
    int* ox  = oy + MAXK;                 // 2^20 x coords

    int* counts = (int*)d_ws;                         // NRS ints
    int* gsum   = counts + NRS;                       // NGRP ints (+pad)
    unsigned short* masks = (unsigned short*)(gsum + NGRP + 16);  // NRS*64 u16

    const size_t need_ws = (size_t)(NRS + NGRP + 16) * sizeof(int)
                         + (size_t)NRS * 64 * sizeof(unsigned short);
    const bool use_masks = ws_size >= need_ws;

    k_maxima<<<NBLK, 256, 0, stream>>>(rel, rep, mx,
                                       use_masks ? masks : nullptr, counts);
    k_gsum<<<NGRP, 64, 0, stream>>>(counts, gsum);
    if (use_masks)
        k_emit_ws<<<NRS / 4, 256, 0, stream>>>(masks, counts, gsum, oy, ox);
    else
        k_emit_mx<<<NRS / 4, 256, 0, stream>>>(mx, counts, gsum, oy, ox);
}

// Round 16
// 46.251 us; speedup vs baseline: 1.4438x; 1.4438x over previous
//
#include <hip/hip_runtime.h>

#define HH 4096
#define WW 4096
#define MAXK (1 << 20)      // == NRS * 32
#define NSP 8               // 512-px spans per row
#define SPW 512             // span width
#define NRS (HH * NSP)      // 32768 row-spans (1 per wave)
#define NBLK (NRS / 4)      // 8192 blocks, 4 waves each
#define GSPAN 512           // spans per group
#define NGRP (NRS / GSPAN)  // 64 groups

typedef int   v4i __attribute__((ext_vector_type(4)));
typedef float v4f __attribute__((ext_vector_type(4)));

// ---------------------------------------------------------------------------
// Kernel 1: 3x3 NMS. One WAVE per 512-px row-span as TWO lane-contiguous
// 256-px panels. Shuffle halo, no LDS, no barriers, no atomics.
// Clamp-to-edge == -inf SAME padding. XCD swizzle for L2 locality.
// rel loads PREDICATED on the candidate nibble. (Round-13 session best.)
// ---------------------------------------------------------------------------
__global__ __launch_bounds__(256, 8) void k_maxima(
    const float* __restrict__ rel, const float* __restrict__ rep,
    int* __restrict__ mx, unsigned char* __restrict__ masks,
    int* __restrict__ counts)
{
    const int tid  = threadIdx.x;
    const int lane = tid & 63;
    const int swz  = (blockIdx.x & 7) * (NBLK / 8) + (blockIdx.x >> 3);
    const int rs   = swz * 4 + (tid >> 6);     // row-span id, 0..NRS-1
    const int y    = rs >> 3;
    const int span = rs & (NSP - 1);
    const int c0   = span * SPW + lane * 4;    // panel-0 column
    const int c1   = c0 + 256;                 // panel-1 column

    const int xl = span ? span * SPW - 1 : 0;                    // left halo col
    const int xr = (span < NSP - 1) ? (span + 1) * SPW : WW - 1; // right halo col
    const int hx = (lane == 63) ? xr : xl;     // 2 cache lines, broadcast

    const float* rowC = rep + (size_t)y * WW;
    const float* rowU = rep + (size_t)(y > 0      ? y - 1 : 0     ) * WW;
    const float* rowD = rep + (size_t)(y < HH - 1 ? y + 1 : HH - 1) * WW;
    const float* rowV = rel + (size_t)y * WW;

    const v4f U0 = *(const v4f*)(rowU + c0), U1 = *(const v4f*)(rowU + c1);
    const v4f C0 = *(const v4f*)(rowC + c0), C1 = *(const v4f*)(rowC + c1);
    const v4f D0 = *(const v4f*)(rowD + c0), D1 = *(const v4f*)(rowD + c1);
    const float hu = rowU[hx], hc = rowC[hx], hd = rowD[hx];
    const float hvm = fmaxf(fmaxf(hu, hc), hd);

    // vertical 3-max, both panels
    const float a0 = fmaxf(fmaxf(U0.x, C0.x), D0.x);
    const float a1 = fmaxf(fmaxf(U0.y, C0.y), D0.y);
    const float a2 = fmaxf(fmaxf(U0.z, C0.z), D0.z);
    const float a3 = fmaxf(fmaxf(U0.w, C0.w), D0.w);
    const float b0 = fmaxf(fmaxf(U1.x, C1.x), D1.x);
    const float b1 = fmaxf(fmaxf(U1.y, C1.y), D1.y);
    const float b2 = fmaxf(fmaxf(U1.z, C1.z), D1.z);
    const float b3 = fmaxf(fmaxf(U1.w, C1.w), D1.w);

    // horizontal halos
    float l0 = __shfl_up(a3, 1, 64);
    float r0 = __shfl_down(a0, 1, 64);
    float l1 = __shfl_up(b3, 1, 64);
    float r1 = __shfl_down(b0, 1, 64);
    const float b0c = __shfl(b0, 0, 64);    // panel1 lane0 vm -> panel0 lane63 right
    const float a3c = __shfl(a3, 63, 64);   // panel0 lane63 vm -> panel1 lane0 left
    if (lane == 0)  { l0 = hvm;  l1 = a3c; }
    if (lane == 63) { r0 = b0c;  r1 = hvm; }

    // candidate nibble: local max AND rep >= 0.7 (rel not consulted yet)
    unsigned int m0 = 0, m1 = 0;
    if (C0.x == fmaxf(fmaxf(l0, a0), a1) && C0.x >= 0.7f) m0 |= 1u;
    if (C0.y == fmaxf(fmaxf(a0, a1), a2) && C0.y >= 0.7f) m0 |= 2u;
    if (C0.z == fmaxf(fmaxf(a1, a2), a3) && C0.z >= 0.7f) m0 |= 4u;
    if (C0.w == fmaxf(fmaxf(a2, a3), r0) && C0.w >= 0.7f) m0 |= 8u;
    if (C1.x == fmaxf(fmaxf(l1, b0), b1) && C1.x >= 0.7f) m1 |= 1u;
    if (C1.y == fmaxf(fmaxf(b0, b1), b2) && C1.y >= 0.7f) m1 |= 2u;
    if (C1.z == fmaxf(fmaxf(b1, b2), b3) && C1.z >= 0.7f) m1 |= 4u;
    if (C1.w == fmaxf(fmaxf(b2, b3), r1) && C1.w >= 0.7f) m1 |= 8u;

    // predicated rel loads: only lanes with a live candidate fetch
    v4f V0 = {0.f, 0.f, 0.f, 0.f}, V1 = {0.f, 0.f, 0.f, 0.f};
    if (m0) V0 = *(const v4f*)(rowV + c0);
    if (m1) V1 = *(const v4f*)(rowV + c1);
    if (!(V0.x >= 0.7f)) m0 &= ~1u;
    if (!(V0.y >= 0.7f)) m0 &= ~2u;
    if (!(V0.z >= 0.7f)) m0 &= ~4u;
    if (!(V0.w >= 0.7f)) m0 &= ~8u;
    if (!(V1.x >= 0.7f)) m1 &= ~1u;
    if (!(V1.y >= 0.7f)) m1 &= ~2u;
    if (!(V1.z >= 0.7f)) m1 &= ~4u;
    if (!(V1.w >= 0.7f)) m1 &= ~8u;

    // maxima as int32 0/1, lane-contiguous, nontemporal (write-once)
    v4i o;
    o.x = m0 & 1u; o.y = (m0 >> 1) & 1u; o.z = (m0 >> 2) & 1u; o.w = (m0 >> 3) & 1u;
    __builtin_nontemporal_store(o, reinterpret_cast<v4i*>(mx + (size_t)y * WW + c0));
    o.x = m1 & 1u; o.y = (m1 >> 1) & 1u; o.z = (m1 >> 2) & 1u; o.w = (m1 >> 3) & 1u;
    __builtin_nontemporal_store(o, reinterpret_cast<v4i*>(mx + (size_t)y * WW + c1));

    if (masks) masks[(size_t)rs * 64 + lane] = (unsigned char)(m0 | (m1 << 4));

    int cnt = __popc(m0 | (m1 << 4));
#pragma unroll
    for (int off = 32; off; off >>= 1) cnt += __shfl_down(cnt, off, 64);
    if (lane == 0) counts[rs] = cnt;
}

// ---------------------------------------------------------------------------
// Kernel 2: per-group sums, NO atomics, fully parallel. 64 blocks x 64
// threads; block g sums counts[g*512 .. g*512+512) -> gsum[g] (one writer).
// ---------------------------------------------------------------------------
__global__ __launch_bounds__(64) void k_gsum(const int* __restrict__ counts,
                                             int* __restrict__ gsum)
{
    const int g    = blockIdx.x;
    const int lane = threadIdx.x;
    const int4* cp = reinterpret_cast<const int4*>(counts + g * GSPAN + lane * 8);
    const int4 a = cp[0], b = cp[1];
    int s = a.x + a.y + a.z + a.w + b.x + b.y + b.z + b.w;
#pragma unroll
    for (int off = 32; off; off >>= 1) s += __shfl_xor(s, off, 64);
    if (lane == 0) gsum[g] = s;
}

// ---------------------------------------------------------------------------
// Offset recomputation (per wave, for span rs):
//   base  = scan(gsum)[group] + sum(counts[group_base .. rs))
//   total = sum(gsum)
// All reads L2-hot (256 B gsum + 2 KB counts slice).
// ---------------------------------------------------------------------------
__device__ __forceinline__ void span_offset(
    const int* __restrict__ counts, const int* __restrict__ gsum,
    int rs, int lane, int& base, int& total)
{
    const int gv = gsum[lane];          // 64 lanes <-> 64 groups
    int ginc = gv;
#pragma unroll
    for (int off = 1; off < 64; off <<= 1) {
        int n = __shfl_up(ginc, off, 64);
        if (lane >= off) ginc += n;
    }
    total = __shfl(ginc, 63, 64);
    const int g     = rs >> 9;
    const int gbase = __shfl(ginc - gv, g, 64);

    const int rl    = rs & (GSPAN - 1);
    const int cbase = rs & ~(GSPAN - 1);
    const int4* cp  = reinterpret_cast<const int4*>(counts + cbase + lane * 8);
    const int4 ca = cp[0], cb = cp[1];
    const int idx = lane * 8;
    int s = 0;
    s += (idx + 0 < rl) ? ca.x : 0;  s += (idx + 1 < rl) ? ca.y : 0;
    s += (idx + 2 < rl) ? ca.z : 0;  s += (idx + 3 < rl) ? ca.w : 0;
    s += (idx + 4 < rl) ? cb.x : 0;  s += (idx + 5 < rl) ? cb.y : 0;
    s += (idx + 6 < rl) ? cb.z : 0;  s += (idx + 7 < rl) ? cb.w : 0;
#pragma unroll
    for (int off = 32; off; off >>= 1) s += __shfl_xor(s, off, 64);
    base = gbase + s;
}

// ---------------------------------------------------------------------------
// Kernel 3a: ordered compaction, one WAVE per 512-px row-span, offsets
// recomputed locally. Fused -1 tail fill: span rs owns slots [rs*32,rs*32+32).
// ---------------------------------------------------------------------------
__global__ __launch_bounds__(256) void k_emit_ws(
    const unsigned char* __restrict__ masks, const int* __restrict__ counts,
    const int* __restrict__ gsum, int* __restrict__ oy, int* __restrict__ ox)
{
    const int tid  = threadIdx.x;
    const int lane = tid & 63;
    const int rs   = blockIdx.x * 4 + (tid >> 6);

    int base, total;
    span_offset(counts, gsum, rs, lane, base, total);

    if (lane < 32) {
        const int slot = rs * 32 + lane;
        if (slot >= total) { oy[slot] = -1; ox[slot] = -1; }
    }

    const unsigned int b = masks[(size_t)rs * 64 + lane];
    unsigned int m0 = b & 0xFu, m1 = b >> 4;
    const int cnt0 = __popc(m0), cnt1 = __popc(m1);

    int inc = cnt0 | (cnt1 << 16);
#pragma unroll
    for (int off = 1; off < 64; off <<= 1) {
        int n = __shfl_up(inc, off, 64);
        if (lane >= off) inc += n;
    }
    const int tot0 = __shfl(inc, 63, 64) & 0xFFFF;
    const int y    = rs >> 3;
    const int xb   = (rs & (NSP - 1)) * SPW + lane * 4;

    int pos = base + (inc & 0xFFFF) - cnt0;          // panel 0
    while (m0) {
        int bit = __ffs(m0) - 1;
        m0 &= m0 - 1;
        if (pos < MAXK) { oy[pos] = y; ox[pos] = xb + bit; }
        ++pos;
    }
    pos = base + tot0 + (inc >> 16) - cnt1;          // panel 1
    while (m1) {
        int bit = __ffs(m1) - 1;
        m1 &= m1 - 1;
        if (pos < MAXK) { oy[pos] = y; ox[pos] = xb + 256 + bit; }
        ++pos;
    }
}

// ---------------------------------------------------------------------------
// Kernel 3b: fallback — rebuild masks from the int32 maxima array.
// ---------------------------------------------------------------------------
__global__ __launch_bounds__(256) void k_emit_mx(
    const int* __restrict__ mx, const int* __restrict__ counts,
    const int* __restrict__ gsum, int* __restrict__ oy, int* __restrict__ ox)
{
    const int tid  = threadIdx.x;
    const int lane = tid & 63;
    const int rs   = blockIdx.x * 4 + (tid >> 6);
    const int y    = rs >> 3;
    const int xb   = (rs & (NSP - 1)) * SPW + lane * 4;

    int base, total;
    span_offset(counts, gsum, rs, lane, base, total);

    if (lane < 32) {
        const int slot = rs * 32 + lane;
        if (slot >= total) { oy[slot] = -1; ox[slot] = -1; }
    }

    const int4 f0 = *reinterpret_cast<const int4*>(mx + (size_t)y * WW + xb);
    const int4 f1 = *reinterpret_cast<const int4*>(mx + (size_t)y * WW + xb + 256);
    unsigned int m0 = 0, m1 = 0;
    if (f0.x) m0 |= 1u;  if (f0.y) m0 |= 2u;  if (f0.z) m0 |= 4u;  if (f0.w) m0 |= 8u;
    if (f1.x) m1 |= 1u;  if (f1.y) m1 |= 2u;  if (f1.z) m1 |= 4u;  if (f1.w) m1 |= 8u;
    const int cnt0 = __popc(m0), cnt1 = __popc(m1);

    int inc = cnt0 | (cnt1 << 16);
#pragma unroll
    for (int off = 1; off < 64; off <<= 1) {
        int n = __shfl_up(inc, off, 64);
        if (lane >= off) inc += n;
    }
    const int tot0 = __shfl(inc, 63, 64) & 0xFFFF;

    int pos = base + (inc & 0xFFFF) - cnt0;
    while (m0) {
        int bit = __ffs(m0) - 1;
        m0 &= m0 - 1;
        if (pos < MAXK) { oy[pos] = y; ox[pos] = xb + bit; }
        ++pos;
    }
    pos = base + tot0 + (inc >> 16) - cnt1;
    while (m1) {
        int bit = __ffs(m1) - 1;
        m1 &= m1 - 1;
        if (pos < MAXK) { oy[pos] = y; ox[pos] = xb + 256 + bit; }
        ++pos;
    }
}

// ---------------------------------------------------------------------------
extern "C" void kernel_launch(void* const* d_in, const int* in_sizes, int n_in,
                              void* d_out, int out_size, void* d_ws, size_t ws_size,
                              hipStream_t stream)
{
    const float* rel = (const float*)d_in[0];   // reliability
    const float* rep = (const float*)d_in[1];   // repeatability

    int* out = (int*)d_out;
    int* mx  = out;                       // 4096*4096 maxima (int32 0/1)
    int* oy  = out + (size_t)HH * WW;     // 2^20 y coords
    int* ox  = oy + MAXK;                 // 2^20 x coords

    int* counts = (int*)d_ws;                         // NRS ints
    int* gsum   = counts + NRS;                       // NGRP ints (+pad)
    unsigned char* masks = (unsigned char*)(gsum + NGRP + 16);  // NRS*64 B

    const size_t need_ws = (size_t)(NRS + NGRP + 16) * sizeof(int)
                         + (size_t)NRS * 64;
    const bool use_masks = ws_size >= need_ws;

    k_maxima<<<NBLK, 256, 0, stream>>>(rel, rep, mx,
                                       use_masks ? masks : nullptr, counts);
    k_gsum<<<NGRP, 64, 0, stream>>>(counts, gsum);
    if (use_masks)
        k_emit_ws<<<NRS / 4, 256, 0, stream>>>(masks, counts, gsum, oy, ox);
    else
        k_emit_mx<<<NRS / 4, 256, 0, stream>>>(mx, counts, gsum, oy, ox);
}